// Round 4
// baseline (107.724 us; speedup 1.0000x reference)
//
#include <hip/hip_runtime.h>
#include <math.h>

#define N_LAYERS 5
#define NG 20

// ---------------------------------------------------------------------------
// Pre-kernel (verified round 2): compose the 20 shared U3 gates + ring CNOTs
// into one 16x16 complex unitary W in d_ws, W[(row*16+col)*2 + {0,1}].
// 256 threads, one amplitude per thread (t = col*16 + row), butterflies via
// __shfl_xor across row bits, CNOTs via shuffled selects. Layer loop ROLLED:
// code ~1.5 KB (v1's 21 KB straight-line body cold-streamed I$ at 63.5 us).
// ---------------------------------------------------------------------------
__global__ __launch_bounds__(256) void compose_W(const float* __restrict__ w,
                                                 float* __restrict__ W) {
    __shared__ float g[NG][8];
    const int t = threadIdx.x;
    if (t < NG) {
        float th = w[t * 3 + 0], ph = w[t * 3 + 1], la = w[t * 3 + 2];
        float st, ct, sl, cl, sp, cp, spl, cpl;
        sincosf(th * 0.5f, &st, &ct);
        sincosf(la, &sl, &cl);
        sincosf(ph, &sp, &cp);
        sincosf(ph + la, &spl, &cpl);
        g[t][0] = ct;        g[t][1] = 0.0f;
        g[t][2] = -cl * st;  g[t][3] = -sl * st;
        g[t][4] = cp * st;   g[t][5] = sp * st;
        g[t][6] = cpl * ct;  g[t][7] = spl * ct;
    }
    __syncthreads();

    const int row = t & 15;   // output basis index (wire0 = bit3)
    const int col = t >> 4;   // input basis column

    float wr = (row == col) ? 1.0f : 0.0f;
    float wi = 0.0f;

#pragma unroll 1
    for (int l = 0; l < N_LAYERS; ++l) {
#pragma unroll
        for (int q = 0; q < 4; ++q) {
            const float* gm = g[l * 4 + q];
            const float m00r = gm[0];
            const float m01r = gm[2], m01i = gm[3];
            const float m10r = gm[4], m10i = gm[5];
            const float m11r = gm[6], m11i = gm[7];
            const int stride = 8 >> q;

            const float pr = __shfl_xor(wr, stride, 64);
            const float pi = __shfl_xor(wi, stride, 64);
            const bool up = (row & stride) != 0;

            const float cAr = up ? m11r : m00r;
            const float cAi = up ? m11i : 0.0f;
            const float cBr = up ? m10r : m01r;
            const float cBi = up ? m10i : m01i;

            const float nr = cAr * wr - cAi * wi + cBr * pr - cBi * pi;
            const float ni = cAr * wi + cAi * wr + cBr * pi + cBi * pr;
            wr = nr; wi = ni;
        }
        // ring CNOTs (0,1)(1,2)(2,3)(3,0): row permutation
#pragma unroll
        for (int e = 0; e < 4; ++e) {
            const int cm = 8 >> e;
            const int tm = 8 >> ((e + 1) & 3);
            const float pr = __shfl_xor(wr, tm, 64);
            const float pi = __shfl_xor(wi, tm, 64);
            if (row & cm) { wr = pr; wi = pi; }
        }
    }

    W[(row * 16 + col) * 2 + 0] = wr;
    W[(row * 16 + col) * 2 + 1] = wi;
}

// ---------------------------------------------------------------------------
// Per-sample encoding: psi0 = v0 (x) v1 (x) v2 (x) v3, 16 complex amps.
// Static indexing throughout -> fully register-allocated after inlining.
// ---------------------------------------------------------------------------
__device__ __forceinline__ void encode(const float4 xv, float* sr, float* si) {
    const float xs[4] = {xv.x, xv.y, xv.z, xv.w};
    float vr[4][2], vi[4][2];
#pragma unroll
    for (int i = 0; i < 4; i++) {
        const float st = __sinf(xs[i] * 0.5f);
        const float ct = __cosf(xs[i] * 0.5f);
        const float sx = __sinf(xs[i]);
        const float cx = __cosf(xs[i]);
        vr[i][0] = ct;      vi[i][0] = 0.0f;
        vr[i][1] = cx * st; vi[i][1] = sx * st;
    }
    float w01r[4], w01i[4], w23r[4], w23i[4];
#pragma unroll
    for (int a = 0; a < 2; a++) {
#pragma unroll
        for (int c = 0; c < 2; c++) {
            w01r[a * 2 + c] = vr[0][a] * vr[1][c] - vi[0][a] * vi[1][c];
            w01i[a * 2 + c] = vr[0][a] * vi[1][c] + vi[0][a] * vr[1][c];
            w23r[a * 2 + c] = vr[2][a] * vr[3][c] - vi[2][a] * vi[3][c];
            w23i[a * 2 + c] = vr[2][a] * vi[3][c] + vi[2][a] * vr[3][c];
        }
    }
#pragma unroll
    for (int hi = 0; hi < 4; hi++) {
#pragma unroll
        for (int lo = 0; lo < 4; lo++) {
            sr[hi * 4 + lo] = w01r[hi] * w23r[lo] - w01i[hi] * w23i[lo];
            si[hi * 4 + lo] = w01r[hi] * w23i[lo] + w01i[hi] * w23r[lo];
        }
    }
}

// ---------------------------------------------------------------------------
// Main kernel: TWO samples per thread (b and b+half, both coalesced).
// W indices are compile-time constants -> uniform address -> s_loads; each
// W scalar (SGPR operand) now feeds 4 FMA chains instead of 2: halves the
// scalar-load pressure per FLOP and doubles ILP. Signs of the <Z_i>
// butterfly folded into the j-loop (round-3-verified arithmetic) to avoid
// p[16] arrays and keep VGPRs ~110.
// ---------------------------------------------------------------------------
__global__ __launch_bounds__(256) void qmain(const float* __restrict__ x,
                                             const float* __restrict__ W,
                                             float* __restrict__ out,
                                             int half) {
    const int b0 = blockIdx.x * 256 + threadIdx.x;
    const int b1 = b0 + half;
    const float4 xvA = ((const float4*)x)[b0];
    const float4 xvB = ((const float4*)x)[b1];

    float srA[16], siA[16], srB[16], siB[16];
    encode(xvA, srA, siA);
    encode(xvB, srB, siB);

    float zA0 = 0.0f, zA1 = 0.0f, zA2 = 0.0f, zA3 = 0.0f;
    float zB0 = 0.0f, zB1 = 0.0f, zB2 = 0.0f, zB3 = 0.0f;

#pragma unroll
    for (int j = 0; j < 16; ++j) {
        float prrA = 0.0f, piiA = 0.0f, prrB = 0.0f, piiB = 0.0f;
#pragma unroll
        for (int k = 0; k < 16; ++k) {
            const float wr = W[(j * 16 + k) * 2 + 0];
            const float wv = W[(j * 16 + k) * 2 + 1];
            prrA = fmaf(wr, srA[k], prrA);
            prrA = fmaf(-wv, siA[k], prrA);
            piiA = fmaf(wr, siA[k], piiA);
            piiA = fmaf(wv, srA[k], piiA);
            prrB = fmaf(wr, srB[k], prrB);
            prrB = fmaf(-wv, siB[k], prrB);
            piiB = fmaf(wr, siB[k], piiB);
            piiB = fmaf(wv, srB[k], piiB);
        }
        const float pA = prrA * prrA + piiA * piiA;
        const float pB = prrB * prrB + piiB * piiB;
        const float s3 = (j & 1) ? -1.0f : 1.0f;
        const float s2 = (j & 2) ? -1.0f : 1.0f;
        const float s1 = (j & 4) ? -1.0f : 1.0f;
        const float s0 = (j & 8) ? -1.0f : 1.0f;
        zA3 = fmaf(s3, pA, zA3);  zB3 = fmaf(s3, pB, zB3);
        zA2 = fmaf(s2, pA, zA2);  zB2 = fmaf(s2, pB, zB2);
        zA1 = fmaf(s1, pA, zA1);  zB1 = fmaf(s1, pB, zB1);
        zA0 = fmaf(s0, pA, zA0);  zB0 = fmaf(s0, pB, zB0);
    }

    ((float4*)out)[b0] = make_float4(zA0, zA1, zA2, zA3);
    ((float4*)out)[b1] = make_float4(zB0, zB1, zB2, zB3);
}

extern "C" void kernel_launch(void* const* d_in, const int* in_sizes, int n_in,
                              void* d_out, int out_size, void* d_ws, size_t ws_size,
                              hipStream_t stream) {
    const float* x = (const float*)d_in[0];   // [B,4] fp32
    const float* w = (const float*)d_in[1];   // [5,4,3] fp32
    float* out = (float*)d_out;               // [B,4] fp32
    float* W = (float*)d_ws;                  // 16*16*2 floats = 2 KB
    const int b = in_sizes[0] / 4;
    const int half = b / 2;

    compose_W<<<1, 256, 0, stream>>>(w, W);
    qmain<<<half / 256, 256, 0, stream>>>(x, W, out, half);
}

// Round 5
// 78.733 us; speedup vs baseline: 1.3682x; 1.3682x over previous
//
#include <hip/hip_runtime.h>
#include <math.h>

#define N_LAYERS 5
#define NG 20

// ---------------------------------------------------------------------------
// Pre-kernel (verified round 2): compose the 20 shared U3 gates + ring CNOTs
// into one 16x16 complex unitary W in d_ws, W[(row*16+col)*2 + {0,1}].
// 256 threads, one amplitude per thread (t = col*16 + row), butterflies via
// __shfl_xor across row bits, CNOTs via shuffled selects. Layer loop ROLLED:
// code ~1.5 KB. (v1 lesson: 21 KB straight-line code = 63.5 us of serial
// cold-I$ streaming — I$ is invalidated per dispatch and the harness's
// 268 MB poison-fill thrashes L2/L3, so code re-streams from HBM.)
// ---------------------------------------------------------------------------
__global__ __launch_bounds__(256) void compose_W(const float* __restrict__ w,
                                                 float* __restrict__ W) {
    __shared__ float g[NG][8];
    const int t = threadIdx.x;
    if (t < NG) {
        float th = w[t * 3 + 0], ph = w[t * 3 + 1], la = w[t * 3 + 2];
        float st, ct, sl, cl, sp, cp, spl, cpl;
        sincosf(th * 0.5f, &st, &ct);
        sincosf(la, &sl, &cl);
        sincosf(ph, &sp, &cp);
        sincosf(ph + la, &spl, &cpl);
        g[t][0] = ct;        g[t][1] = 0.0f;
        g[t][2] = -cl * st;  g[t][3] = -sl * st;
        g[t][4] = cp * st;   g[t][5] = sp * st;
        g[t][6] = cpl * ct;  g[t][7] = spl * ct;
    }
    __syncthreads();

    const int row = t & 15;   // output basis index (wire0 = bit3)
    const int col = t >> 4;   // input basis column

    float wr = (row == col) ? 1.0f : 0.0f;
    float wi = 0.0f;

#pragma unroll 1
    for (int l = 0; l < N_LAYERS; ++l) {
#pragma unroll
        for (int q = 0; q < 4; ++q) {
            const float* gm = g[l * 4 + q];
            const float m00r = gm[0];
            const float m01r = gm[2], m01i = gm[3];
            const float m10r = gm[4], m10i = gm[5];
            const float m11r = gm[6], m11i = gm[7];
            const int stride = 8 >> q;

            const float pr = __shfl_xor(wr, stride, 64);
            const float pi = __shfl_xor(wi, stride, 64);
            const bool up = (row & stride) != 0;

            const float cAr = up ? m11r : m00r;
            const float cAi = up ? m11i : 0.0f;
            const float cBr = up ? m10r : m01r;
            const float cBi = up ? m10i : m01i;

            const float nr = cAr * wr - cAi * wi + cBr * pr - cBi * pi;
            const float ni = cAr * wi + cAi * wr + cBr * pi + cBi * pr;
            wr = nr; wi = ni;
        }
        // ring CNOTs (0,1)(1,2)(2,3)(3,0): row permutation
#pragma unroll
        for (int e = 0; e < 4; ++e) {
            const int cm = 8 >> e;
            const int tm = 8 >> ((e + 1) & 3);
            const float pr = __shfl_xor(wr, tm, 64);
            const float pi = __shfl_xor(wi, tm, 64);
            if (row & cm) { wr = pr; wi = pi; }
        }
    }

    W[(row * 16 + col) * 2 + 0] = wr;
    W[(row * 16 + col) * 2 + 1] = wi;
}

// ---------------------------------------------------------------------------
// Main kernel: ONE sample per thread (round-2 structure — round-4's 2-sample
// unrolled variant was 20 KB of code and cold-streamed I$ per CU per
// dispatch: FETCH 4.45 MB ~= code x CUs, 50 us).
//
// v5: j-loop ROLLED (unroll 2) -> code ~3 KB total. Per row j: one 32-dword
// W row via scalar loads (uniform dynamic offset j*128B -> s_load, W stays
// an SGPR operand of every FMA: zero VALU/DS cost for gate delivery), 64
// FMAs, then the <Z_i> butterfly signs folded in (round-3-verified
// arithmetic; per-k FMA order identical to all passing versions).
// ---------------------------------------------------------------------------
__global__ __launch_bounds__(256) void qmain(const float* __restrict__ x,
                                             const float* __restrict__ W,
                                             float* __restrict__ out) {
    const int b = blockIdx.x * 256 + threadIdx.x;
    const float4 xv = ((const float4*)x)[b];
    const float xs[4] = {xv.x, xv.y, xv.z, xv.w};

    // encoding columns: [cos(x/2), e^{ix} sin(x/2)]
    float vr[4][2], vi[4][2];
#pragma unroll
    for (int i = 0; i < 4; i++) {
        const float st = __sinf(xs[i] * 0.5f);
        const float ct = __cosf(xs[i] * 0.5f);
        const float sx = __sinf(xs[i]);
        const float cx = __cosf(xs[i]);
        vr[i][0] = ct;      vi[i][0] = 0.0f;
        vr[i][1] = cx * st; vi[i][1] = sx * st;
    }

    // tensor product -> 16 complex amps (wire0 = bit3)
    float w01r[4], w01i[4], w23r[4], w23i[4];
#pragma unroll
    for (int a = 0; a < 2; a++) {
#pragma unroll
        for (int c = 0; c < 2; c++) {
            w01r[a * 2 + c] = vr[0][a] * vr[1][c] - vi[0][a] * vi[1][c];
            w01i[a * 2 + c] = vr[0][a] * vi[1][c] + vi[0][a] * vr[1][c];
            w23r[a * 2 + c] = vr[2][a] * vr[3][c] - vi[2][a] * vi[3][c];
            w23i[a * 2 + c] = vr[2][a] * vi[3][c] + vi[2][a] * vr[3][c];
        }
    }
    float sr[16], si[16];
#pragma unroll
    for (int hi = 0; hi < 4; hi++) {
#pragma unroll
        for (int lo = 0; lo < 4; lo++) {
            sr[hi * 4 + lo] = w01r[hi] * w23r[lo] - w01i[hi] * w23i[lo];
            si[hi * 4 + lo] = w01r[hi] * w23i[lo] + w01i[hi] * w23r[lo];
        }
    }

    // psi_j = sum_k W[j][k] * s_k ; |psi_j|^2 ; signs folded into j-loop.
    float z0 = 0.0f, z1 = 0.0f, z2 = 0.0f, z3 = 0.0f;
#pragma unroll 2
    for (int j = 0; j < 16; ++j) {
        const float* __restrict__ Wrow = W + j * 32;   // uniform -> s_load
        float prr = 0.0f, pii = 0.0f;
#pragma unroll
        for (int k = 0; k < 16; ++k) {
            const float wr = Wrow[k * 2 + 0];
            const float wv = Wrow[k * 2 + 1];
            prr = fmaf(wr, sr[k], prr);
            prr = fmaf(-wv, si[k], prr);
            pii = fmaf(wr, si[k], pii);
            pii = fmaf(wv, sr[k], pii);
        }
        const float pj = prr * prr + pii * pii;
        const float s3 = (j & 1) ? -1.0f : 1.0f;
        const float s2 = (j & 2) ? -1.0f : 1.0f;
        const float s1 = (j & 4) ? -1.0f : 1.0f;
        const float s0 = (j & 8) ? -1.0f : 1.0f;
        z3 = fmaf(s3, pj, z3);
        z2 = fmaf(s2, pj, z2);
        z1 = fmaf(s1, pj, z1);
        z0 = fmaf(s0, pj, z0);
    }

    ((float4*)out)[b] = make_float4(z0, z1, z2, z3);
}

extern "C" void kernel_launch(void* const* d_in, const int* in_sizes, int n_in,
                              void* d_out, int out_size, void* d_ws, size_t ws_size,
                              hipStream_t stream) {
    const float* x = (const float*)d_in[0];   // [B,4] fp32
    const float* w = (const float*)d_in[1];   // [5,4,3] fp32
    float* out = (float*)d_out;               // [B,4] fp32
    float* W = (float*)d_ws;                  // 16*16*2 floats = 2 KB
    const int b = in_sizes[0] / 4;

    compose_W<<<1, 256, 0, stream>>>(w, W);
    qmain<<<b / 256, 256, 0, stream>>>(x, W, out);
}

// Round 6
// 76.523 us; speedup vs baseline: 1.4077x; 1.0289x over previous
//
#include <hip/hip_runtime.h>
#include <math.h>

#define N_LAYERS 5
#define NG 20

typedef float v2f __attribute__((ext_vector_type(2)));

// ---------------------------------------------------------------------------
// Pre-kernel (verified round 2, layout v2): compose the 20 shared U3 gates +
// ring CNOTs into one 16x16 complex unitary. 256 threads, one amplitude per
// thread (t = col*16 + row), butterflies via __shfl_xor across row bits,
// CNOTs via shuffled selects, layer loop ROLLED (code ~1.5 KB; v1 lesson:
// 21 KB straight-line code cold-streamed I$ at 63.5 us).
//
// NEW LAYOUT (for packed-FMA qmain): row j stored plane-separated,
//   W[j*32 + k]      = Re W[j][k]   (k = 0..15)
//   W[j*32 + 16 + k] = Im W[j][k]
// so (re_k, re_{k+1}) / (im_k, im_{k+1}) are ADJACENT dwords -> SGPR pairs
// usable directly as v_pk_fma_f32 sources.
// ---------------------------------------------------------------------------
__global__ __launch_bounds__(256) void compose_W(const float* __restrict__ w,
                                                 float* __restrict__ W) {
    __shared__ float g[NG][8];
    const int t = threadIdx.x;
    if (t < NG) {
        float th = w[t * 3 + 0], ph = w[t * 3 + 1], la = w[t * 3 + 2];
        float st, ct, sl, cl, sp, cp, spl, cpl;
        sincosf(th * 0.5f, &st, &ct);
        sincosf(la, &sl, &cl);
        sincosf(ph, &sp, &cp);
        sincosf(ph + la, &spl, &cpl);
        g[t][0] = ct;        g[t][1] = 0.0f;
        g[t][2] = -cl * st;  g[t][3] = -sl * st;
        g[t][4] = cp * st;   g[t][5] = sp * st;
        g[t][6] = cpl * ct;  g[t][7] = spl * ct;
    }
    __syncthreads();

    const int row = t & 15;   // output basis index (wire0 = bit3)
    const int col = t >> 4;   // input basis column

    float wr = (row == col) ? 1.0f : 0.0f;
    float wi = 0.0f;

#pragma unroll 1
    for (int l = 0; l < N_LAYERS; ++l) {
#pragma unroll
        for (int q = 0; q < 4; ++q) {
            const float* gm = g[l * 4 + q];
            const float m00r = gm[0];
            const float m01r = gm[2], m01i = gm[3];
            const float m10r = gm[4], m10i = gm[5];
            const float m11r = gm[6], m11i = gm[7];
            const int stride = 8 >> q;

            const float pr = __shfl_xor(wr, stride, 64);
            const float pi = __shfl_xor(wi, stride, 64);
            const bool up = (row & stride) != 0;

            const float cAr = up ? m11r : m00r;
            const float cAi = up ? m11i : 0.0f;
            const float cBr = up ? m10r : m01r;
            const float cBi = up ? m10i : m01i;

            const float nr = cAr * wr - cAi * wi + cBr * pr - cBi * pi;
            const float ni = cAr * wi + cAi * wr + cBr * pi + cBi * pr;
            wr = nr; wi = ni;
        }
        // ring CNOTs (0,1)(1,2)(2,3)(3,0): row permutation
#pragma unroll
        for (int e = 0; e < 4; ++e) {
            const int cm = 8 >> e;
            const int tm = 8 >> ((e + 1) & 3);
            const float pr = __shfl_xor(wr, tm, 64);
            const float pi = __shfl_xor(wi, tm, 64);
            if (row & cm) { wr = pr; wi = pi; }
        }
    }

    W[row * 32 + col]      = wr;   // Re plane
    W[row * 32 + 16 + col] = wi;   // Im plane
}

// ---------------------------------------------------------------------------
// Main kernel: ONE sample per thread (R2 structure, best measured), j-loop
// FULLY unrolled (R5's rolled loop regressed: per-iter s_load waits), but
// the 1024 scalar FMAs are replaced by 512 packed v_pk_fma_f32: even/odd-k
// partial sums accumulate in float2 pairs, W re/im pairs come straight from
// adjacent SGPRs (uniform address -> s_load; zero VALU/DS cost for gate
// delivery — the load-bearing trick, preserved). Worst case the backend
// splits the vector fma into 2x v_fma_f32 == exactly the old code.
// ---------------------------------------------------------------------------
__global__ __launch_bounds__(256) void qmain(const float* __restrict__ x,
                                             const float* __restrict__ W,
                                             float* __restrict__ out) {
    const int b = blockIdx.x * 256 + threadIdx.x;
    const float4 xv = ((const float4*)x)[b];
    const float xs[4] = {xv.x, xv.y, xv.z, xv.w};

    // encoding columns: [cos(x/2), e^{ix} sin(x/2)]
    float vr[4][2], vi[4][2];
#pragma unroll
    for (int i = 0; i < 4; i++) {
        const float st = __sinf(xs[i] * 0.5f);
        const float ct = __cosf(xs[i] * 0.5f);
        const float sx = __sinf(xs[i]);
        const float cx = __cosf(xs[i]);
        vr[i][0] = ct;      vi[i][0] = 0.0f;
        vr[i][1] = cx * st; vi[i][1] = sx * st;
    }

    // tensor product -> 16 complex amps (wire0 = bit3), packed as 8 v2f pairs
    float w01r[4], w01i[4], w23r[4], w23i[4];
#pragma unroll
    for (int a = 0; a < 2; a++) {
#pragma unroll
        for (int c = 0; c < 2; c++) {
            w01r[a * 2 + c] = vr[0][a] * vr[1][c] - vi[0][a] * vi[1][c];
            w01i[a * 2 + c] = vr[0][a] * vi[1][c] + vi[0][a] * vr[1][c];
            w23r[a * 2 + c] = vr[2][a] * vr[3][c] - vi[2][a] * vi[3][c];
            w23i[a * 2 + c] = vr[2][a] * vi[3][c] + vi[2][a] * vr[3][c];
        }
    }
    v2f sr2[8], si2[8];   // sr2[k>>1][k&1] = Re psi0_k, etc.
#pragma unroll
    for (int hi = 0; hi < 4; hi++) {
#pragma unroll
        for (int lo = 0; lo < 4; lo++) {
            const int i = hi * 4 + lo;
            sr2[i >> 1][i & 1] = w01r[hi] * w23r[lo] - w01i[hi] * w23i[lo];
            si2[i >> 1][i & 1] = w01r[hi] * w23i[lo] + w01i[hi] * w23r[lo];
        }
    }

    // psi_j = sum_k W[j][k] * psi0_k, even/odd k lanes packed; p_j = |psi_j|^2
    const v2f* __restrict__ Wv = (const v2f*)W;   // row j: re pairs [j*16..+7], im pairs [j*16+8..+15]
    float p[16];
#pragma unroll
    for (int j = 0; j < 16; ++j) {
        v2f ar = {0.0f, 0.0f}, ai = {0.0f, 0.0f};
#pragma unroll
        for (int k2 = 0; k2 < 8; ++k2) {
            const v2f wr2 = Wv[j * 16 + k2];       // (re_k, re_{k+1})  uniform -> s_load
            const v2f wi2 = Wv[j * 16 + 8 + k2];   // (im_k, im_{k+1})
            ar = __builtin_elementwise_fma(wr2, sr2[k2], ar);
            ar = __builtin_elementwise_fma(-wi2, si2[k2], ar);
            ai = __builtin_elementwise_fma(wr2, si2[k2], ai);
            ai = __builtin_elementwise_fma(wi2, sr2[k2], ai);
        }
        const float prr = ar.x + ar.y;
        const float pii = ai.x + ai.y;
        p[j] = fmaf(prr, prr, pii * pii);
    }

    // butterfly signed reduction: bit0=wire3 ... bit3=wire0 (R0/R2-exact)
    const float a0 = p[0] + p[1],   a1 = p[2] + p[3],   a2 = p[4] + p[5],   a3 = p[6] + p[7];
    const float a4 = p[8] + p[9],   a5 = p[10] + p[11], a6 = p[12] + p[13], a7 = p[14] + p[15];
    const float z3 = (p[0] - p[1]) + (p[2] - p[3]) + (p[4] - p[5]) + (p[6] - p[7])
                   + (p[8] - p[9]) + (p[10] - p[11]) + (p[12] - p[13]) + (p[14] - p[15]);
    const float b0 = a0 + a1, b1 = a2 + a3, b2 = a4 + a5, b3 = a6 + a7;
    const float z2 = (a0 - a1) + (a2 - a3) + (a4 - a5) + (a6 - a7);
    const float c0 = b0 + b1, c1 = b2 + b3;
    const float z1 = (b0 - b1) + (b2 - b3);
    const float z0 = c0 - c1;

    ((float4*)out)[b] = make_float4(z0, z1, z2, z3);
}

extern "C" void kernel_launch(void* const* d_in, const int* in_sizes, int n_in,
                              void* d_out, int out_size, void* d_ws, size_t ws_size,
                              hipStream_t stream) {
    const float* x = (const float*)d_in[0];   // [B,4] fp32
    const float* w = (const float*)d_in[1];   // [5,4,3] fp32
    float* out = (float*)d_out;               // [B,4] fp32
    float* W = (float*)d_ws;                  // 16*32 floats = 2 KB (plane-separated rows)
    const int b = in_sizes[0] / 4;

    compose_W<<<1, 256, 0, stream>>>(w, W);
    qmain<<<b / 256, 256, 0, stream>>>(x, W, out);
}

// Round 7
// 75.506 us; speedup vs baseline: 1.4267x; 1.0135x over previous
//
#include <hip/hip_runtime.h>
#include <math.h>

#define N_LAYERS 5
#define NG 20

typedef float v2f __attribute__((ext_vector_type(2)));

// ---------------------------------------------------------------------------
// I$-front mitigation: every CU re-streams the kernel's code from HBM every
// dispatch (R4 evidence: FETCH 4455 KB ~= 20 KB code x 222 ~= per-CU; the
// harness's 268 MB poison-fill evicts L2+L3 each iteration, and I$ misses
// are SERIAL at ~0.19 us/64B line -> code size x 0.19 predicts R0/R3/R4/R5/R6
// durations). Data loads are 64-lane PARALLEL: touch the code region as data
// at kernel entry (s_getpc + 1 dword/lane at 64 B stride), keep the value
// alive until kernel end, so the I$ walk hits L3/L2 instead of HBM.
// Window is conservative (pc-256 .. +~4/8 KB) to stay inside the loaded ELF.
// ---------------------------------------------------------------------------
__device__ __forceinline__ float code_warm_4k() {
    unsigned long long pc;
    asm volatile("s_getpc_b64 %0" : "=s"(pc));
    const unsigned long long base = (pc - 256ULL) & ~63ULL;
    const float* p = (const float*)(base + (unsigned long long)((threadIdx.x & 63) << 6));
    return *p;                      // 64 lanes x 64 B = 4 KB of code lines
}
__device__ __forceinline__ float code_warm_8k() {
    unsigned long long pc;
    asm volatile("s_getpc_b64 %0" : "=s"(pc));
    const unsigned long long base = (pc - 256ULL) & ~63ULL;
    const float* p = (const float*)(base + (unsigned long long)((threadIdx.x & 63) << 6));
    return p[0] + p[1024];          // two 4 KB rounds
}

// ---------------------------------------------------------------------------
// Pre-kernel (verified R2/R6): compose the 20 shared U3 gates + ring CNOTs
// into one 16x16 complex unitary. 256 threads, one amplitude per thread
// (t = col*16 + row), butterflies via __shfl_xor across row bits, CNOTs via
// shuffled selects, layer loop ROLLED (code ~1.5 KB).
// Layout (R6): row j plane-separated: W[j*32+k]=Re, W[j*32+16+k]=Im.
// ---------------------------------------------------------------------------
__global__ __launch_bounds__(256) void compose_W(const float* __restrict__ w,
                                                 float* __restrict__ W) {
    const float warm = code_warm_8k();   // also reaches into qmain's code

    __shared__ float g[NG][8];
    const int t = threadIdx.x;
    if (t < NG) {
        float th = w[t * 3 + 0], ph = w[t * 3 + 1], la = w[t * 3 + 2];
        float st, ct, sl, cl, sp, cp, spl, cpl;
        sincosf(th * 0.5f, &st, &ct);
        sincosf(la, &sl, &cl);
        sincosf(ph, &sp, &cp);
        sincosf(ph + la, &spl, &cpl);
        g[t][0] = ct;        g[t][1] = 0.0f;
        g[t][2] = -cl * st;  g[t][3] = -sl * st;
        g[t][4] = cp * st;   g[t][5] = sp * st;
        g[t][6] = cpl * ct;  g[t][7] = spl * ct;
    }
    __syncthreads();

    const int row = t & 15;   // output basis index (wire0 = bit3)
    const int col = t >> 4;   // input basis column

    float wr = (row == col) ? 1.0f : 0.0f;
    float wi = 0.0f;

#pragma unroll 1
    for (int l = 0; l < N_LAYERS; ++l) {
#pragma unroll
        for (int q = 0; q < 4; ++q) {
            const float* gm = g[l * 4 + q];
            const float m00r = gm[0];
            const float m01r = gm[2], m01i = gm[3];
            const float m10r = gm[4], m10i = gm[5];
            const float m11r = gm[6], m11i = gm[7];
            const int stride = 8 >> q;

            const float pr = __shfl_xor(wr, stride, 64);
            const float pi = __shfl_xor(wi, stride, 64);
            const bool up = (row & stride) != 0;

            const float cAr = up ? m11r : m00r;
            const float cAi = up ? m11i : 0.0f;
            const float cBr = up ? m10r : m01r;
            const float cBi = up ? m10i : m01i;

            const float nr = cAr * wr - cAi * wi + cBr * pr - cBi * pi;
            const float ni = cAr * wi + cAi * wr + cBr * pi + cBi * pr;
            wr = nr; wi = ni;
        }
        // ring CNOTs (0,1)(1,2)(2,3)(3,0): row permutation
#pragma unroll
        for (int e = 0; e < 4; ++e) {
            const int cm = 8 >> e;
            const int tm = 8 >> ((e + 1) & 3);
            const float pr = __shfl_xor(wr, tm, 64);
            const float pi = __shfl_xor(wi, tm, 64);
            if (row & cm) { wr = pr; wi = pi; }
        }
    }

    W[row * 32 + col]      = wr;   // Re plane
    W[row * 32 + 16 + col] = wi;   // Im plane

    asm volatile("" :: "v"(warm)); // keep prefetch alive to kernel end
}

// ---------------------------------------------------------------------------
// Main kernel: byte-identical body to R6 (one sample/thread, full-unroll
// packed matvec, W via uniform s_loads = SGPR operands — the load-bearing
// trick), plus the 4 KB code-warm at entry.
// ---------------------------------------------------------------------------
__global__ __launch_bounds__(256) void qmain(const float* __restrict__ x,
                                             const float* __restrict__ W,
                                             float* __restrict__ out) {
    const float warm = code_warm_4k();

    const int b = blockIdx.x * 256 + threadIdx.x;
    const float4 xv = ((const float4*)x)[b];
    const float xs[4] = {xv.x, xv.y, xv.z, xv.w};

    // encoding columns: [cos(x/2), e^{ix} sin(x/2)]
    float vr[4][2], vi[4][2];
#pragma unroll
    for (int i = 0; i < 4; i++) {
        const float st = __sinf(xs[i] * 0.5f);
        const float ct = __cosf(xs[i] * 0.5f);
        const float sx = __sinf(xs[i]);
        const float cx = __cosf(xs[i]);
        vr[i][0] = ct;      vi[i][0] = 0.0f;
        vr[i][1] = cx * st; vi[i][1] = sx * st;
    }

    // tensor product -> 16 complex amps (wire0 = bit3), packed as 8 v2f pairs
    float w01r[4], w01i[4], w23r[4], w23i[4];
#pragma unroll
    for (int a = 0; a < 2; a++) {
#pragma unroll
        for (int c = 0; c < 2; c++) {
            w01r[a * 2 + c] = vr[0][a] * vr[1][c] - vi[0][a] * vi[1][c];
            w01i[a * 2 + c] = vr[0][a] * vi[1][c] + vi[0][a] * vr[1][c];
            w23r[a * 2 + c] = vr[2][a] * vr[3][c] - vi[2][a] * vi[3][c];
            w23i[a * 2 + c] = vr[2][a] * vi[3][c] + vi[2][a] * vr[3][c];
        }
    }
    v2f sr2[8], si2[8];   // sr2[k>>1][k&1] = Re psi0_k, etc.
#pragma unroll
    for (int hi = 0; hi < 4; hi++) {
#pragma unroll
        for (int lo = 0; lo < 4; lo++) {
            const int i = hi * 4 + lo;
            sr2[i >> 1][i & 1] = w01r[hi] * w23r[lo] - w01i[hi] * w23i[lo];
            si2[i >> 1][i & 1] = w01r[hi] * w23i[lo] + w01i[hi] * w23r[lo];
        }
    }

    // psi_j = sum_k W[j][k] * psi0_k, even/odd k lanes packed; p_j = |psi_j|^2
    const v2f* __restrict__ Wv = (const v2f*)W;   // row j: re pairs [j*16..+7], im pairs [j*16+8..+15]
    float p[16];
#pragma unroll
    for (int j = 0; j < 16; ++j) {
        v2f ar = {0.0f, 0.0f}, ai = {0.0f, 0.0f};
#pragma unroll
        for (int k2 = 0; k2 < 8; ++k2) {
            const v2f wr2 = Wv[j * 16 + k2];       // (re_k, re_{k+1})  uniform -> s_load
            const v2f wi2 = Wv[j * 16 + 8 + k2];   // (im_k, im_{k+1})
            ar = __builtin_elementwise_fma(wr2, sr2[k2], ar);
            ar = __builtin_elementwise_fma(-wi2, si2[k2], ar);
            ai = __builtin_elementwise_fma(wr2, si2[k2], ai);
            ai = __builtin_elementwise_fma(wi2, sr2[k2], ai);
        }
        const float prr = ar.x + ar.y;
        const float pii = ai.x + ai.y;
        p[j] = fmaf(prr, prr, pii * pii);
    }

    // butterfly signed reduction: bit0=wire3 ... bit3=wire0 (R0/R2-exact)
    const float a0 = p[0] + p[1],   a1 = p[2] + p[3],   a2 = p[4] + p[5],   a3 = p[6] + p[7];
    const float a4 = p[8] + p[9],   a5 = p[10] + p[11], a6 = p[12] + p[13], a7 = p[14] + p[15];
    const float z3 = (p[0] - p[1]) + (p[2] - p[3]) + (p[4] - p[5]) + (p[6] - p[7])
                   + (p[8] - p[9]) + (p[10] - p[11]) + (p[12] - p[13]) + (p[14] - p[15]);
    const float b0 = a0 + a1, b1 = a2 + a3, b2 = a4 + a5, b3 = a6 + a7;
    const float z2 = (a0 - a1) + (a2 - a3) + (a4 - a5) + (a6 - a7);
    const float c0 = b0 + b1, c1 = b2 + b3;
    const float z1 = (b0 - b1) + (b2 - b3);
    const float z0 = c0 - c1;

    ((float4*)out)[b] = make_float4(z0, z1, z2, z3);

    asm volatile("" :: "v"(warm)); // keep prefetch alive to kernel end
}

extern "C" void kernel_launch(void* const* d_in, const int* in_sizes, int n_in,
                              void* d_out, int out_size, void* d_ws, size_t ws_size,
                              hipStream_t stream) {
    const float* x = (const float*)d_in[0];   // [B,4] fp32
    const float* w = (const float*)d_in[1];   // [5,4,3] fp32
    float* out = (float*)d_out;               // [B,4] fp32
    float* W = (float*)d_ws;                  // 16*32 floats = 2 KB (plane-separated rows)
    const int b = in_sizes[0] / 4;

    compose_W<<<1, 256, 0, stream>>>(w, W);
    qmain<<<b / 256, 256, 0, stream>>>(x, W, out);
}